// Round 5
// baseline (135.548 us; speedup 1.0000x reference)
//
#include <hip/hip_runtime.h>

// S=32 systems, N=512 atoms/system, F=256 features
#define SY 32
#define NA 512
#define FD 256

typedef __attribute__((ext_vector_type(8))) short bf16x8;   // 8 bf16 = 4 VGPRs
typedef __attribute__((ext_vector_type(4))) short bf16x4;   // 4 bf16 = 8 B
typedef __attribute__((ext_vector_type(4))) float f32x4;    // MFMA C/D frag

static __device__ __forceinline__ short f2bf(float x) {
    union { float f; unsigned u; } v; v.f = x;
    unsigned r = v.u + 0x7fffu + ((v.u >> 16) & 1u);   // RNE
    return (short)(r >> 16);
}
static __device__ __forceinline__ float bf2f(short x) {
    union { float f; unsigned u; } v;
    v.u = ((unsigned)(unsigned short)x) << 16;
    return v.f;
}

// async 16B global->LDS (linear dest = wave-uniform base + lane*16)
static __device__ __forceinline__ void gld16(const void* g, void* l) {
    __builtin_amdgcn_global_load_lds(
        (const __attribute__((address_space(1))) void*)g,
        (__attribute__((address_space(3))) void*)l,
        16, 0, 0);
}

// ---------------------------------------------------------------------------
// Kernel 1 (validated round 3): charges = features @ W^T + b via bf16 MFMA.
// 512 blocks x 256 threads, 32-row tiles, LDS 41.5 KB -> 2 blocks/CU.
// Writes qT bf16 [s][f][j] into the UPPER HALF of d_out (no workspace use).
// Also zero-initializes the lr arrival counter (d_out element 0) — the
// kernel boundary orders this before lr reads it.
// ---------------------------------------------------------------------------
__global__ __launch_bounds__(256, 2) void charges_v2(
    const float* __restrict__ feat, const float* __restrict__ W,
    const float* __restrict__ b, short* __restrict__ qT,
    unsigned* __restrict__ ctr)
{
    __shared__ __attribute__((aligned(16))) short sA[32 * 72];   //  4.6 KB
    __shared__ __attribute__((aligned(16))) short sB[256 * 72];  // 36.9 KB
    short* tr = sB;                          // epilogue reuse: 256*40 shorts
    const int t    = threadIdx.x;
    const int i0   = blockIdx.x * 32;        // 512 blocks x 32 rows
    const int w    = t >> 6;                 // wave 0..3
    const int lane = t & 63;
    const int n16  = lane & 15;
    const int quad = lane >> 4;

    if (blockIdx.x == 0 && t == 0)
        __hip_atomic_store(ctr, 0u, __ATOMIC_RELAXED, __HIP_MEMORY_SCOPE_AGENT);

    f32x4 acc[2][4];
    #pragma unroll
    for (int a = 0; a < 2; ++a)
        #pragma unroll
        for (int c = 0; c < 4; ++c) acc[a][c] = (f32x4)0.0f;

    for (int k0 = 0; k0 < FD; k0 += 64) {
        // stage feat tile 32i x 64k (2 float4/thread)
        #pragma unroll
        for (int m = 0; m < 2; ++m) {
            int lin = t + 256 * m;
            int i = lin >> 4, kq = lin & 15;
            float4 v = *(const float4*)&feat[(size_t)(i0 + i) * FD + k0 + 4 * kq];
            bf16x4 p; p[0] = f2bf(v.x); p[1] = f2bf(v.y);
                      p[2] = f2bf(v.z); p[3] = f2bf(v.w);
            *(bf16x4*)&sA[i * 72 + 4 * kq] = p;
        }
        // stage W tile 256f x 64k (16 float4/thread)
        #pragma unroll
        for (int m = 0; m < 16; ++m) {
            int lin = t + 256 * m;
            int f = lin >> 4, kq = lin & 15;
            float4 v = *(const float4*)&W[(size_t)f * FD + k0 + 4 * kq];
            bf16x4 p; p[0] = f2bf(v.x); p[1] = f2bf(v.y);
                      p[2] = f2bf(v.z); p[3] = f2bf(v.w);
            *(bf16x4*)&sB[f * 72 + 4 * kq] = p;
        }
        __syncthreads();

        #pragma unroll
        for (int ks = 0; ks < 64; ks += 32) {
            bf16x8 af[2], bfr[4];
            #pragma unroll
            for (int it = 0; it < 2; ++it)
                af[it] = *(const bf16x8*)&sA[(16 * it + n16) * 72 + ks + quad * 8];
            #pragma unroll
            for (int fb = 0; fb < 4; ++fb)
                bfr[fb] = *(const bf16x8*)&sB[(64 * w + 16 * fb + n16) * 72 + ks + quad * 8];
            __builtin_amdgcn_s_setprio(1);
            #pragma unroll
            for (int it = 0; it < 2; ++it)
                #pragma unroll
                for (int fb = 0; fb < 4; ++fb)
                    acc[it][fb] = __builtin_amdgcn_mfma_f32_16x16x32_bf16(
                        af[it], bfr[fb], acc[it][fb], 0, 0, 0);
            __builtin_amdgcn_s_setprio(0);
        }
        __syncthreads();
    }

    float bias[4];
    #pragma unroll
    for (int fb = 0; fb < 4; ++fb) bias[fb] = b[64 * w + 16 * fb + n16];

    // transpose to [f][i] bf16 (pitch 40) in reused sB, then 16B stores
    #pragma unroll
    for (int it = 0; it < 2; ++it)
        #pragma unroll
        for (int fb = 0; fb < 4; ++fb) {
            bf16x4 p;
            #pragma unroll
            for (int r = 0; r < 4; ++r) p[r] = f2bf(acc[it][fb][r] + bias[fb]);
            int f = 64 * w + 16 * fb + n16;
            *(bf16x4*)&tr[f * 40 + 16 * it + 4 * quad] = p;
        }
    __syncthreads();
    {
        short* qTs = qT + ((size_t)(i0 >> 9)) * FD * NA;
        const int ilb = i0 & 511;
        #pragma unroll
        for (int n = 0; n < 4; ++n) {
            int S = n * 256 + t;        // 0..1023
            int f = S >> 2;             // 0..255
            int c = S & 3;              // chunk of 8 atoms
            uint4 v = *(const uint4*)&tr[f * 40 + c * 8];
            *(uint4*)&qTs[(size_t)f * NA + ilb + c * 8] = v;
        }
    }
}

// ---------------------------------------------------------------------------
// Kernel 2: V = 0.5 * v @ q (bf16 MFMA), out = V * q. NON-cooperative.
// Identical j-loop to the validated round-1/3 lr_fast. qT lives in the
// upper half of d_out. WAR (epilogue overwrites qT region other blocks
// still read) is ordered by a hand-rolled arrival barrier:
//   - grid 512 == exact co-residency capacity (78 KB LDS -> 2 blocks/CU
//     x 256 CU), so all blocks are resident simultaneously;
//   - each block arrives only after its last __syncthreads (which drains
//     vmcnt(0) -> all its qT reads already landed in LDS/registers);
//   - device-scope atomic counter (d_out[0], zeroed by charges_v2);
//   - bounded spin as a fail-soft valve (no hang if assumption breaks).
// ---------------------------------------------------------------------------
__global__ __launch_bounds__(256, 2) void lr_fast(
    const float* __restrict__ pos, float* __restrict__ gbuf,
    const short* __restrict__ qT, unsigned* __restrict__ ctr)
{
    __shared__ float px[NA], py[NA], pz[NA];
    __shared__ __attribute__((aligned(16))) short sqb[FD * 128];  // 64 KB [f][128j swz]
    __shared__ __attribute__((aligned(16))) short svb[32 * 128];  //  8 KB [i][128j swz]

    const int blk = blockIdx.x;
    const int s   = blk & 31;
    const int i0  = (blk >> 5) * 32;
    const int t   = threadIdx.x;
    const int w    = t >> 6;
    const int lane = t & 63;
    const int n16  = lane & 15;
    const int quad = lane >> 4;

    for (int m = t; m < NA; m += 256) {
        const float* p = &pos[((size_t)s * NA + m) * 3];
        px[m] = p[0]; py[m] = p[1]; pz[m] = p[2];
    }

    f32x4 acc[2][4];
    #pragma unroll
    for (int a = 0; a < 2; ++a)
        #pragma unroll
        for (int c = 0; c < 4; ++c) acc[a][c] = (f32x4)0.0f;
    float qreg[2][4][4];

    const short* qTs = qT + (size_t)s * FD * NA;
    const int pi = t & 31;        // pair-tile i
    const int pc = t >> 5;        // pair-tile j-chunk 0..7 (16 j each)
    const int gi = i0 + pi;
    const int wbase = t & ~63;    // w*64, wave-uniform

    __syncthreads();
    const float xi = px[gi], yi = py[gi], zi = pz[gi];

    for (int j0 = 0; j0 < NA; j0 += 128) {
        // ---- stage q tile: 256f x 128j bf16 via global_load_lds -----------
        // linear LDS slot Sl = n*256 + t holds row f=Sl>>4, phys chunk cs=Sl&15,
        // sourced from logical chunk c=(cs-f)&15 -> read swizzle is (c+f)&15.
        #pragma unroll
        for (int n = 0; n < 16; ++n) {
            int Sl = n * 256 + t;
            int f  = Sl >> 4;
            int cs = Sl & 15;
            int c  = (cs - f) & 15;
            gld16(&qTs[(size_t)f * NA + j0 + c * 8],
                  &sqb[(n * 256 + wbase) * 8]);     // uniform base + lane*16
        }
        // ---- v tile: 32i x 128j (16 pair evals/thread, hides load lat) ----
        bf16x8 vA, vB;
        #pragma unroll
        for (int jj = 0; jj < 8; ++jj) {
            int gj = j0 + pc * 16 + jj;
            float dx = xi - px[gj];
            float dy = yi - py[gj];
            float dz = zi - pz[gj];
            float r2 = dx * dx + dy * dy + dz * dz;
            float inv = __builtin_amdgcn_rsqf(r2);
            float dd  = r2 * inv;
            float sn = __sinf(dd * 0.31415926535f);
            float om = (dd < 5.0f) ? sn * sn : 1.0f;
            float vv = (gi != gj) ? 0.5f * om * inv : 0.0f;
            vA[jj] = f2bf(vv);
        }
        #pragma unroll
        for (int jj = 0; jj < 8; ++jj) {
            int gj = j0 + pc * 16 + 8 + jj;
            float dx = xi - px[gj];
            float dy = yi - py[gj];
            float dz = zi - pz[gj];
            float r2 = dx * dx + dy * dy + dz * dz;
            float inv = __builtin_amdgcn_rsqf(r2);
            float dd  = r2 * inv;
            float sn = __sinf(dd * 0.31415926535f);
            float om = (dd < 5.0f) ? sn * sn : 1.0f;
            float vv = (gi != gj) ? 0.5f * om * inv : 0.0f;
            vB[jj] = f2bf(vv);
        }
        *(bf16x8*)&svb[pi * 128 + (((2 * pc + pi) & 15) * 8)]     = vA;
        *(bf16x8*)&svb[pi * 128 + (((2 * pc + 1 + pi) & 15) * 8)] = vB;
        __syncthreads();

        // ---- own-tile q snapshot (once; uniform branch) ----
        if (j0 == (i0 & ~127)) {
            const int jb0 = i0 & 127;     // 0,32,64,96
            #pragma unroll
            for (int it = 0; it < 2; ++it)
                #pragma unroll
                for (int fb = 0; fb < 4; ++fb) {
                    int f = 64 * w + 16 * fb + n16;
                    #pragma unroll
                    for (int r = 0; r < 4; ++r) {
                        int jl = jb0 + 16 * it + 4 * quad + r;
                        int c  = jl >> 3, o = jl & 7;
                        qreg[it][fb][r] =
                            bf2f(sqb[f * 128 + (((c + f) & 15) * 8) + o]);
                    }
                }
        }

        // ---- fragments + MFMA: 4 kh x (2 it x 4 fb) = 32 mfma / wave ----
        #pragma unroll
        for (int kh = 0; kh < 4; ++kh) {
            const int c = kh * 4 + quad;          // logical 8-j chunk 0..15
            bf16x8 a0 = *(const bf16x8*)&svb[n16 * 128 + (((c + n16) & 15) * 8)];
            bf16x8 a1 = *(const bf16x8*)&svb[(16 + n16) * 128 + (((c + 16 + n16) & 15) * 8)];
            bf16x8 bq[4];
            #pragma unroll
            for (int fb = 0; fb < 4; ++fb) {
                int f = 64 * w + 16 * fb + n16;
                bq[fb] = *(const bf16x8*)&sqb[f * 128 + (((c + f) & 15) * 8)];
            }
            __builtin_amdgcn_s_setprio(1);
            #pragma unroll
            for (int fb = 0; fb < 4; ++fb) {
                acc[0][fb] = __builtin_amdgcn_mfma_f32_16x16x32_bf16(
                    a0, bq[fb], acc[0][fb], 0, 0, 0);
                acc[1][fb] = __builtin_amdgcn_mfma_f32_16x16x32_bf16(
                    a1, bq[fb], acc[1][fb], 0, 0, 0);
            }
            __builtin_amdgcn_s_setprio(0);
        }
        __syncthreads();
    }

    // ---- arrival barrier: all qT reads are complete (drained into LDS/regs
    // at the last __syncthreads). Wait for all 512 blocks before overwriting
    // the qT region. Bounded spin = fail-soft valve.
    if (t == 0) {
        __hip_atomic_fetch_add(ctr, 1u, __ATOMIC_ACQ_REL, __HIP_MEMORY_SCOPE_AGENT);
        unsigned v; int guard = 0;
        do {
            v = __hip_atomic_load(ctr, __ATOMIC_ACQUIRE, __HIP_MEMORY_SCOPE_AGENT);
        } while (v < 512u && ++guard < (1 << 16));
    }
    __syncthreads();

    // epilogue: out = V * q  (pure store, q from registers)
    #pragma unroll
    for (int it = 0; it < 2; ++it)
        #pragma unroll
        for (int fb = 0; fb < 4; ++fb)
            #pragma unroll
            for (int r = 0; r < 4; ++r) {
                int i = i0 + 16 * it + 4 * quad + r;
                int f = 64 * w + 16 * fb + n16;
                size_t a = ((size_t)s * NA + i) * FD + f;
                gbuf[a] = acc[it][fb][r] * qreg[it][fb][r];
            }
}

extern "C" void kernel_launch(void* const* d_in, const int* in_sizes, int n_in,
                              void* d_out, int out_size, void* d_ws, size_t ws_size,
                              hipStream_t stream) {
    const float* positions = (const float*)d_in[0];  // [32,512,3]
    const float* features  = (const float*)d_in[1];  // [16384,256]
    const float* W         = (const float*)d_in[2];  // [256,256]
    const float* b         = (const float*)d_in[3];  // [256]
    float* gbuf = (float*)d_out;

    // qT bf16 [32][256][512] = 8,388,608 B = exactly the upper half of d_out
    // (16,777,216 B). Workspace deliberately UNUSED (fill-conditionality test).
    short* qT = (short*)d_out + (size_t)SY * FD * NA;   // byte offset 8 MiB
    unsigned* ctr = (unsigned*)d_out;                    // zeroed by charges_v2

    charges_v2<<<dim3(512), 256, 0, stream>>>(features, W, b, qT, ctr);
    lr_fast<<<dim3(512), 256, 0, stream>>>(positions, gbuf, qT, ctr);
}

// Round 7
// 110.680 us; speedup vs baseline: 1.2247x; 1.2247x over previous
//
#include <hip/hip_runtime.h>
#include <hip/hip_cooperative_groups.h>

// S=32 systems, N=512 atoms/system, F=256 features
#define SY 32
#define NA 512
#define FD 256

typedef __attribute__((ext_vector_type(8))) short bf16x8;   // 8 bf16 = 4 VGPRs
typedef __attribute__((ext_vector_type(4))) short bf16x4;   // 4 bf16 = 8 B
typedef __attribute__((ext_vector_type(4))) float f32x4;    // MFMA C/D frag

static __device__ __forceinline__ short f2bf(float x) {
    union { float f; unsigned u; } v; v.f = x;
    unsigned r = v.u + 0x7fffu + ((v.u >> 16) & 1u);   // RNE
    return (short)(r >> 16);
}
static __device__ __forceinline__ float bf2f(short x) {
    union { float f; unsigned u; } v;
    v.u = ((unsigned)(unsigned short)x) << 16;
    return v.f;
}

// ---------------------------------------------------------------------------
// Kernel 1 v6: charges = features @ W^T + b via bf16 MFMA (fp32 accum).
// 512 blocks x 256 threads, 32-row tiles.
// Changes vs round-3 (latency diet, same math / same index maps):
//  - W fragments load DIRECT global->VGPR (wave w only ever consumed rows
//    64w..64w+63 of the staged tile => staging had zero cross-wave reuse,
//    pure overhead). W is 256 KB, L2/L3-resident.
//  - feat tile keeps LDS staging (4x cross-wave reuse) but is double-
//    buffered -> ONE barrier per k-iteration instead of two.
//  - LDS: sA 2x4.6 KB + tr 20 KB = 29 KB.
// ---------------------------------------------------------------------------
__global__ __launch_bounds__(256, 2) void charges_v2(
    const float* __restrict__ feat, const float* __restrict__ W,
    const float* __restrict__ b, short* __restrict__ qT)
{
    __shared__ __attribute__((aligned(16))) short sA[2][32 * 72]; // 9.2 KB
    __shared__ __attribute__((aligned(16))) short tr[256 * 40];   // 20 KB
    const int t    = threadIdx.x;
    const int i0   = blockIdx.x * 32;        // 512 blocks x 32 rows
    const int w    = t >> 6;                 // wave 0..3
    const int lane = t & 63;
    const int n16  = lane & 15;
    const int quad = lane >> 4;

    f32x4 acc[2][4];
    #pragma unroll
    for (int a = 0; a < 2; ++a)
        #pragma unroll
        for (int c = 0; c < 4; ++c) acc[a][c] = (f32x4)0.0f;

    int cur = 0;
    for (int k0 = 0; k0 < FD; k0 += 64) {
        // stage feat tile 32i x 64k into sA[cur] (2 float4/thread)
        #pragma unroll
        for (int m = 0; m < 2; ++m) {
            int lin = t + 256 * m;
            int i = lin >> 4, kq = lin & 15;
            float4 v = *(const float4*)&feat[(size_t)(i0 + i) * FD + k0 + 4 * kq];
            bf16x4 p; p[0] = f2bf(v.x); p[1] = f2bf(v.y);
                      p[2] = f2bf(v.z); p[3] = f2bf(v.w);
            *(bf16x4*)&sA[cur][i * 72 + 4 * kq] = p;
        }
        __syncthreads();   // sA[cur] ready; prior-iter readers of sA[cur^1] done

        #pragma unroll
        for (int ks = 0; ks < 64; ks += 32) {
            bf16x8 af[2];
            #pragma unroll
            for (int it = 0; it < 2; ++it)
                af[it] = *(const bf16x8*)&sA[cur][(16 * it + n16) * 72 + ks + quad * 8];
            // W fragments: direct global f32 -> bf16x8 (rows 64w+16fb+n16)
            bf16x8 bfr[4];
            #pragma unroll
            for (int fb = 0; fb < 4; ++fb) {
                const float* wp = &W[(size_t)(64 * w + 16 * fb + n16) * FD
                                     + k0 + ks + quad * 8];
                float4 w0 = *(const float4*)wp;
                float4 w1 = *(const float4*)(wp + 4);
                bf16x8 p;
                p[0] = f2bf(w0.x); p[1] = f2bf(w0.y);
                p[2] = f2bf(w0.z); p[3] = f2bf(w0.w);
                p[4] = f2bf(w1.x); p[5] = f2bf(w1.y);
                p[6] = f2bf(w1.z); p[7] = f2bf(w1.w);
                bfr[fb] = p;
            }
            __builtin_amdgcn_s_setprio(1);
            #pragma unroll
            for (int it = 0; it < 2; ++it)
                #pragma unroll
                for (int fb = 0; fb < 4; ++fb)
                    acc[it][fb] = __builtin_amdgcn_mfma_f32_16x16x32_bf16(
                        af[it], bfr[fb], acc[it][fb], 0, 0, 0);
            __builtin_amdgcn_s_setprio(0);
        }
        cur ^= 1;
    }

    float bias[4];
    #pragma unroll
    for (int fb = 0; fb < 4; ++fb) bias[fb] = b[64 * w + 16 * fb + n16];

    // transpose to [f][i] bf16 (pitch 40) in tr, then coalesced 16B stores
    #pragma unroll
    for (int it = 0; it < 2; ++it)
        #pragma unroll
        for (int fb = 0; fb < 4; ++fb) {
            bf16x4 p;
            #pragma unroll
            for (int r = 0; r < 4; ++r) p[r] = f2bf(acc[it][fb][r] + bias[fb]);
            int f = 64 * w + 16 * fb + n16;
            *(bf16x4*)&tr[f * 40 + 16 * it + 4 * quad] = p;
        }
    __syncthreads();
    {
        short* qTs = qT + ((size_t)(i0 >> 9)) * FD * NA;
        const int ilb = i0 & 511;
        #pragma unroll
        for (int n = 0; n < 4; ++n) {
            int S = n * 256 + t;        // 0..1023
            int f = S >> 2;             // 0..255
            int c = S & 3;              // chunk of 8 atoms
            uint4 v = *(const uint4*)&tr[f * 40 + c * 8];
            *(uint4*)&qTs[(size_t)f * NA + ilb + c * 8] = v;
        }
    }
}

// ---------------------------------------------------------------------------
// Kernel 2 v6: V = 0.5 * v @ q (bf16 MFMA), out = V * q. Non-coop, qT in d_ws.
// Latency diet vs round-3 (same math / same validated index maps):
//  - q LDS staging DELETED: wave w only ever read sqb rows 64w..64w+63
//    (zero cross-wave reuse) -> B fragments now load DIRECT global->VGPR
//    as bf16x8 from qT[f][j] (fragment-shaped; 16 full 64B lines / wave op).
//    Removes 16 gld16 + vmcnt(0) drain + 16 ds_read + swizzle per iter.
//  - own-tile q snapshot: direct bf16x4 global loads before the loop
//    (removes in-loop uniform branch).
//  - svb (v-tile, genuinely shared by all 4 waves) double-buffered ->
//    ONE barrier per j-iteration. LDS total: 6 KB pos + 16 KB svb = 22 KB.
// ---------------------------------------------------------------------------
__global__ __launch_bounds__(256, 2) void lr_fast(
    const float* __restrict__ pos, float* __restrict__ gbuf,
    const short* __restrict__ qT)
{
    __shared__ float px[NA], py[NA], pz[NA];
    __shared__ __attribute__((aligned(16))) short svb[2][32 * 128]; // 16 KB

    const int blk = blockIdx.x;
    const int s   = blk & 31;          // XCD-local: 16 blocks of s on XCD s%8
    const int i0  = (blk >> 5) * 32;
    const int t   = threadIdx.x;
    const int w    = t >> 6;
    const int lane = t & 63;
    const int n16  = lane & 15;
    const int quad = lane >> 4;

    for (int m = t; m < NA; m += 256) {
        const float* p = &pos[((size_t)s * NA + m) * 3];
        px[m] = p[0]; py[m] = p[1]; pz[m] = p[2];
    }

    f32x4 acc[2][4];
    #pragma unroll
    for (int a = 0; a < 2; ++a)
        #pragma unroll
        for (int c = 0; c < 4; ++c) acc[a][c] = (f32x4)0.0f;

    const short* qTs = qT + (size_t)s * FD * NA;

    // own-tile q snapshot: qreg[it][fb][r] = q[f][i0+16it+4quad+r], direct.
    float qreg[2][4][4];
    #pragma unroll
    for (int it = 0; it < 2; ++it)
        #pragma unroll
        for (int fb = 0; fb < 4; ++fb) {
            int f = 64 * w + 16 * fb + n16;
            bf16x4 qv = *(const bf16x4*)&qTs[(size_t)f * NA + i0 + 16 * it + 4 * quad];
            #pragma unroll
            for (int r = 0; r < 4; ++r) qreg[it][fb][r] = bf2f(qv[r]);
        }

    const int pi = t & 31;        // pair-tile i
    const int pc = t >> 5;        // pair-tile j-chunk 0..7 (16 j each)
    const int gi = i0 + pi;

    __syncthreads();              // positions ready
    const float xi = px[gi], yi = py[gi], zi = pz[gi];

    int cur = 0;
    for (int j0 = 0; j0 < NA; j0 += 128) {
        // ---- v tile: 32i x 128j (16 pair evals/thread) into svb[cur] ----
        bf16x8 vA, vB;
        #pragma unroll
        for (int jj = 0; jj < 8; ++jj) {
            int gj = j0 + pc * 16 + jj;
            float dx = xi - px[gj];
            float dy = yi - py[gj];
            float dz = zi - pz[gj];
            float r2 = dx * dx + dy * dy + dz * dz;
            float inv = __builtin_amdgcn_rsqf(r2);
            float dd  = r2 * inv;
            float sn = __sinf(dd * 0.31415926535f);
            float om = (dd < 5.0f) ? sn * sn : 1.0f;
            float vv = (gi != gj) ? 0.5f * om * inv : 0.0f;
            vA[jj] = f2bf(vv);
        }
        #pragma unroll
        for (int jj = 0; jj < 8; ++jj) {
            int gj = j0 + pc * 16 + 8 + jj;
            float dx = xi - px[gj];
            float dy = yi - py[gj];
            float dz = zi - pz[gj];
            float r2 = dx * dx + dy * dy + dz * dz;
            float inv = __builtin_amdgcn_rsqf(r2);
            float dd  = r2 * inv;
            float sn = __sinf(dd * 0.31415926535f);
            float om = (dd < 5.0f) ? sn * sn : 1.0f;
            float vv = (gi != gj) ? 0.5f * om * inv : 0.0f;
            vB[jj] = f2bf(vv);
        }
        *(bf16x8*)&svb[cur][pi * 128 + (((2 * pc + pi) & 15) * 8)]     = vA;
        *(bf16x8*)&svb[cur][pi * 128 + (((2 * pc + 1 + pi) & 15) * 8)] = vB;
        __syncthreads();   // svb[cur] ready; prior readers of svb[cur^1] done

        // ---- fragments + MFMA: 4 kh x (2 it x 4 fb) = 32 mfma / wave ----
        #pragma unroll
        for (int kh = 0; kh < 4; ++kh) {
            const int c = kh * 4 + quad;          // logical 8-j chunk 0..15
            bf16x8 a0 = *(const bf16x8*)&svb[cur][n16 * 128 + (((c + n16) & 15) * 8)];
            bf16x8 a1 = *(const bf16x8*)&svb[cur][(16 + n16) * 128 + (((c + 16 + n16) & 15) * 8)];
            // q fragments: DIRECT global bf16x8, rows 64w+16fb+n16
            bf16x8 bq[4];
            #pragma unroll
            for (int fb = 0; fb < 4; ++fb) {
                int f = 64 * w + 16 * fb + n16;
                bq[fb] = *(const bf16x8*)&qTs[(size_t)f * NA + j0 + c * 8];
            }
            __builtin_amdgcn_s_setprio(1);
            #pragma unroll
            for (int fb = 0; fb < 4; ++fb) {
                acc[0][fb] = __builtin_amdgcn_mfma_f32_16x16x32_bf16(
                    a0, bq[fb], acc[0][fb], 0, 0, 0);
                acc[1][fb] = __builtin_amdgcn_mfma_f32_16x16x32_bf16(
                    a1, bq[fb], acc[1][fb], 0, 0, 0);
            }
            __builtin_amdgcn_s_setprio(0);
        }
        cur ^= 1;
    }

    // epilogue: out = V * q  (pure store, q from registers)
    #pragma unroll
    for (int it = 0; it < 2; ++it)
        #pragma unroll
        for (int fb = 0; fb < 4; ++fb)
            #pragma unroll
            for (int r = 0; r < 4; ++r) {
                int i = i0 + 16 * it + 4 * quad + r;
                int f = 64 * w + 16 * fb + n16;
                size_t a = ((size_t)s * NA + i) * FD + f;
                gbuf[a] = acc[it][fb][r] * qreg[it][fb][r];
            }
}

// ---------------------------------------------------------------------------
// FALLBACK kernels (used if ws < 8 MB) — unchanged, validated earlier.
// ---------------------------------------------------------------------------
__global__ __launch_bounds__(512) void charges_mfma(
    const float* __restrict__ feat, const float* __restrict__ W,
    const float* __restrict__ b, float* __restrict__ qfp,
    short* __restrict__ qT)
{
    __shared__ __attribute__((aligned(16))) short sA[64 * 72];
    __shared__ __attribute__((aligned(16))) short sB[256 * 72];
    __shared__ __attribute__((aligned(16))) short tr[256 * 72];
    const int t    = threadIdx.x;
    const int i0   = blockIdx.x * 64;
    const int w    = t >> 6;
    const int lane = t & 63;
    const int n16  = lane & 15;
    const int quad = lane >> 4;

    f32x4 acc[4][2];
    #pragma unroll
    for (int a = 0; a < 4; ++a)
        #pragma unroll
        for (int c = 0; c < 2; ++c) acc[a][c] = (f32x4)0.0f;

    for (int k0 = 0; k0 < FD; k0 += 64) {
        #pragma unroll
        for (int m = 0; m < 2; ++m) {
            int lin = t + 512 * m;
            int i = lin >> 4, kq = lin & 15;
            float4 v = *(const float4*)&feat[(size_t)(i0 + i) * FD + k0 + 4 * kq];
            bf16x4 p; p[0] = f2bf(v.x); p[1] = f2bf(v.y);
                      p[2] = f2bf(v.z); p[3] = f2bf(v.w);
            *(bf16x4*)&sA[i * 72 + 4 * kq] = p;
        }
        #pragma unroll
        for (int m = 0; m < 8; ++m) {
            int lin = t + 512 * m;
            int f = lin >> 4, kq = lin & 15;
            float4 v = *(const float4*)&W[(size_t)f * FD + k0 + 4 * kq];
            bf16x4 p; p[0] = f2bf(v.x); p[1] = f2bf(v.y);
                      p[2] = f2bf(v.z); p[3] = f2bf(v.w);
            *(bf16x4*)&sB[f * 72 + 4 * kq] = p;
        }
        __syncthreads();

        #pragma unroll
        for (int ks = 0; ks < 64; ks += 32) {
            bf16x8 af[4], bfr[2];
            #pragma unroll
            for (int it = 0; it < 4; ++it)
                af[it] = *(const bf16x8*)&sA[(16 * it + n16) * 72 + ks + quad * 8];
            #pragma unroll
            for (int fb = 0; fb < 2; ++fb)
                bfr[fb] = *(const bf16x8*)&sB[(32 * w + 16 * fb + n16) * 72 + ks + quad * 8];
            #pragma unroll
            for (int it = 0; it < 4; ++it)
                #pragma unroll
                for (int fb = 0; fb < 2; ++fb)
                    acc[it][fb] = __builtin_amdgcn_mfma_f32_16x16x32_bf16(
                        af[it], bfr[fb], acc[it][fb], 0, 0, 0);
        }
        __syncthreads();
    }

    float bias[2];
    #pragma unroll
    for (int fb = 0; fb < 2; ++fb) bias[fb] = b[32 * w + 16 * fb + n16];

    if (qfp) {
        #pragma unroll
        for (int it = 0; it < 4; ++it)
            #pragma unroll
            for (int fb = 0; fb < 2; ++fb)
                #pragma unroll
                for (int r = 0; r < 4; ++r) {
                    int i = i0 + 16 * it + 4 * quad + r;
                    int f = 32 * w + 16 * fb + n16;
                    qfp[(size_t)i * FD + f] = acc[it][fb][r] + bias[fb];
                }
    }

    #pragma unroll
    for (int it = 0; it < 4; ++it)
        #pragma unroll
        for (int fb = 0; fb < 2; ++fb) {
            bf16x4 p;
            #pragma unroll
            for (int r = 0; r < 4; ++r) p[r] = f2bf(acc[it][fb][r] + bias[fb]);
            int f = 32 * w + 16 * fb + n16;
            *(bf16x4*)&tr[f * 72 + 16 * it + 4 * quad] = p;
        }
    __syncthreads();
    {
        short* qTs = qT + ((size_t)(i0 >> 9)) * FD * NA;
        const int ilb = i0 & 511;
        #pragma unroll
        for (int n = 0; n < 4; ++n) {
            int S = n * 512 + t;
            int f = S >> 3;
            int c = S & 7;
            uint4 v = *(const uint4*)&tr[f * 72 + c * 8];
            *(uint4*)&qTs[(size_t)f * NA + ilb + c * 8] = v;
        }
    }
}

__global__ __launch_bounds__(256) void lr_coop(
    const float* __restrict__ pos, float* __restrict__ gbuf)
{
    __shared__ float px[NA], py[NA], pz[NA];
    __shared__ __attribute__((aligned(16))) short svb[64 * 40];
    __shared__ __attribute__((aligned(16))) short sqb[FD * 40];

    const int blk = blockIdx.x;
    const int s   = blk & 31;
    const int i0  = (blk >> 5) * 64;
    const int t   = threadIdx.x;
    const int w    = t >> 6;
    const int lane = t & 63;
    const int n16  = lane & 15;
    const int quad = lane >> 4;

    for (int m = t; m < NA; m += 256) {
        const float* p = &pos[((size_t)s * NA + m) * 3];
        px[m] = p[0]; py[m] = p[1]; pz[m] = p[2];
    }

    f32x4 acc[4][4];
    #pragma unroll
    for (int a = 0; a < 4; ++a)
        #pragma unroll
        for (int c = 0; c < 4; ++c) acc[a][c] = (f32x4)0.0f;

    __syncthreads();

    const int fq  = t >> 2;
    const int jb  = t & 3;
    const int iv  = t & 63;
    const int jbv = t >> 6;
    const int gi  = i0 + iv;

    float4 rq[8];
    #pragma unroll
    for (int m = 0; m < 8; ++m)
        rq[m] = *(const float4*)&gbuf[((size_t)s * NA + 8 * jb + m) * FD + 4 * fq];

    for (int j0 = 0; j0 < NA; j0 += 32) {
        bf16x8 vrow;
        #pragma unroll
        for (int jj = 0; jj < 8; ++jj) {
            int gj = j0 + 8 * jbv + jj;
            float dx = px[gi] - px[gj];
            float dy = py[gi] - py[gj];
            float dz = pz[gi] - pz[gj];
            float dd = sqrtf(dx * dx + dy * dy + dz * dz);
            float om = (dd < 5.0f) ? 0.5f * (1.0f - __cosf(dd * 0.62831853071795f))
                                   : 1.0f;
            float vv = (gi != gj) ? (0.5f * om * __builtin_amdgcn_rcpf(dd)) : 0.0f;
            vrow[jj] = f2bf(vv);
        }
        bf16x8 rows[4];
        #pragma unroll
        for (int m = 0; m < 8; ++m) {
            rows[0][m] = f2bf(rq[m].x);
            rows[1][m] = f2bf(rq[m].y);
            rows[2][m] = f2bf(rq[m].z);
            rows[3][m] = f2bf(rq[m].w);
        }
        #pragma unroll
        for (int d = 0; d < 4; ++d) {
            int f = 4 * fq + d;
            int phys = (jb + (f >> 3)) & 3;
            *(bf16x8*)&sqb[f * 40 + phys * 8] = rows[d];
        }
        {
            int phys = (jbv + (iv >> 3)) & 3;
            *(bf16x8*)&svb[iv * 40 + phys * 8] = vrow;
        }
        {
            int jn = (j0 + 32) & (NA - 1);
            #pragma unroll
            for (int m = 0; m < 8; ++m)
                rq[m] = *(const float4*)&gbuf[((size_t)s * NA + jn + 8 * jb + m) * FD + 4 * fq];
        }
        __syncthreads();

        bf16x8 af[4], bfr[4];
        #pragma unroll
        for (int it = 0; it < 4; ++it) {
            int i = 16 * it + n16;
            int phys = (quad + (i >> 3)) & 3;
            af[it] = *(const bf16x8*)&svb[i * 40 + phys * 8];
        }
        #pragma unroll
        for (int fb = 0; fb < 4; ++fb) {
            int f = 16 * (4 * w + fb) + n16;
            int phys = (quad + (f >> 3)) & 3;
            bfr[fb] = *(const bf16x8*)&sqb[f * 40 + phys * 8];
        }
        #pragma unroll
        for (int it = 0; it < 4; ++it)
            #pragma unroll
            for (int fb = 0; fb < 4; ++fb)
                acc[it][fb] = __builtin_amdgcn_mfma_f32_16x16x32_bf16(
                    af[it], bfr[fb], acc[it][fb], 0, 0, 0);
        __syncthreads();
    }

    cooperative_groups::this_grid().sync();

    #pragma unroll
    for (int it = 0; it < 4; ++it)
        #pragma unroll
        for (int fb = 0; fb < 4; ++fb)
            #pragma unroll
            for (int r = 0; r < 4; ++r) {
                int i = i0 + 16 * it + 4 * quad + r;
                int f = 16 * (4 * w + fb) + n16;
                size_t a = ((size_t)s * NA + i) * FD + f;
                gbuf[a] = acc[it][fb][r] * gbuf[a];
            }
}

extern "C" void kernel_launch(void* const* d_in, const int* in_sizes, int n_in,
                              void* d_out, int out_size, void* d_ws, size_t ws_size,
                              hipStream_t stream) {
    const float* positions = (const float*)d_in[0];  // [32,512,3]
    const float* features  = (const float*)d_in[1];  // [16384,256]
    const float* W         = (const float*)d_in[2];  // [256,256]
    const float* b         = (const float*)d_in[3];  // [256]
    float* gbuf = (float*)d_out;

    const size_t qT_bytes = (size_t)SY * NA * FD * sizeof(short);  // 8 MB
    const bool fast = (ws_size >= qT_bytes);
    short* qT = fast ? (short*)d_ws : nullptr;

    if (fast) {
        charges_v2<<<dim3(512), 256, 0, stream>>>(features, W, b, qT);
        lr_fast<<<dim3(512), 256, 0, stream>>>(positions, gbuf, qT);
    } else {
        // fallback: q fp32 in d_out, cooperative in-place update
        charges_mfma<<<dim3(256), 512, 0, stream>>>(features, W, b, gbuf,
                                                    (short*)d_out /*unused-safe*/);
        void* args[] = {(void*)&positions, (void*)&gbuf};
        hipLaunchCooperativeKernel((void*)lr_coop, dim3(256), dim3(256),
                                   args, 0, stream);
    }
}

// Round 8
// 102.295 us; speedup vs baseline: 1.3251x; 1.0820x over previous
//
#include <hip/hip_runtime.h>
#include <hip/hip_cooperative_groups.h>

// S=32 systems, N=512 atoms/system, F=256 features
#define SY 32
#define NA 512
#define FD 256

typedef __attribute__((ext_vector_type(8))) short bf16x8;   // 8 bf16 = 4 VGPRs
typedef __attribute__((ext_vector_type(4))) short bf16x4;   // 4 bf16 = 8 B
typedef __attribute__((ext_vector_type(4))) float f32x4;    // MFMA C/D frag

static __device__ __forceinline__ short f2bf(float x) {
    union { float f; unsigned u; } v; v.f = x;
    unsigned r = v.u + 0x7fffu + ((v.u >> 16) & 1u);   // RNE
    return (short)(r >> 16);
}
static __device__ __forceinline__ float bf2f(short x) {
    union { float f; unsigned u; } v;
    v.u = ((unsigned)(unsigned short)x) << 16;
    return v.f;
}

// ---------------------------------------------------------------------------
// Kernel 1 (EXACT round-3 revert, validated 96.5 µs config):
// charges = features @ W^T + b via bf16 MFMA (fp32 accum).
// 512 blocks x 256 threads, 32-row tiles, LDS 41.5 KB -> 2 blocks/CU.
// ---------------------------------------------------------------------------
__global__ __launch_bounds__(256, 2) void charges_v2(
    const float* __restrict__ feat, const float* __restrict__ W,
    const float* __restrict__ b, short* __restrict__ qT)
{
    __shared__ __attribute__((aligned(16))) short sA[32 * 72];   //  4.6 KB
    __shared__ __attribute__((aligned(16))) short sB[256 * 72];  // 36.9 KB
    short* tr = sB;                          // epilogue reuse: 256*40 shorts
    const int t    = threadIdx.x;
    const int i0   = blockIdx.x * 32;        // 512 blocks x 32 rows
    const int w    = t >> 6;                 // wave 0..3
    const int lane = t & 63;
    const int n16  = lane & 15;
    const int quad = lane >> 4;

    f32x4 acc[2][4];
    #pragma unroll
    for (int a = 0; a < 2; ++a)
        #pragma unroll
        for (int c = 0; c < 4; ++c) acc[a][c] = (f32x4)0.0f;

    for (int k0 = 0; k0 < FD; k0 += 64) {
        // stage feat tile 32i x 64k (2 float4/thread)
        #pragma unroll
        for (int m = 0; m < 2; ++m) {
            int lin = t + 256 * m;
            int i = lin >> 4, kq = lin & 15;
            float4 v = *(const float4*)&feat[(size_t)(i0 + i) * FD + k0 + 4 * kq];
            bf16x4 p; p[0] = f2bf(v.x); p[1] = f2bf(v.y);
                      p[2] = f2bf(v.z); p[3] = f2bf(v.w);
            *(bf16x4*)&sA[i * 72 + 4 * kq] = p;
        }
        // stage W tile 256f x 64k (16 float4/thread)
        #pragma unroll
        for (int m = 0; m < 16; ++m) {
            int lin = t + 256 * m;
            int f = lin >> 4, kq = lin & 15;
            float4 v = *(const float4*)&W[(size_t)f * FD + k0 + 4 * kq];
            bf16x4 p; p[0] = f2bf(v.x); p[1] = f2bf(v.y);
                      p[2] = f2bf(v.z); p[3] = f2bf(v.w);
            *(bf16x4*)&sB[f * 72 + 4 * kq] = p;
        }
        __syncthreads();

        #pragma unroll
        for (int ks = 0; ks < 64; ks += 32) {
            bf16x8 af[2], bfr[4];
            #pragma unroll
            for (int it = 0; it < 2; ++it)
                af[it] = *(const bf16x8*)&sA[(16 * it + n16) * 72 + ks + quad * 8];
            #pragma unroll
            for (int fb = 0; fb < 4; ++fb)
                bfr[fb] = *(const bf16x8*)&sB[(64 * w + 16 * fb + n16) * 72 + ks + quad * 8];
            __builtin_amdgcn_s_setprio(1);
            #pragma unroll
            for (int it = 0; it < 2; ++it)
                #pragma unroll
                for (int fb = 0; fb < 4; ++fb)
                    acc[it][fb] = __builtin_amdgcn_mfma_f32_16x16x32_bf16(
                        af[it], bfr[fb], acc[it][fb], 0, 0, 0);
            __builtin_amdgcn_s_setprio(0);
        }
        __syncthreads();
    }

    float bias[4];
    #pragma unroll
    for (int fb = 0; fb < 4; ++fb) bias[fb] = b[64 * w + 16 * fb + n16];

    // transpose to [f][i] bf16 (pitch 40) in reused sB, then 16B stores
    #pragma unroll
    for (int it = 0; it < 2; ++it)
        #pragma unroll
        for (int fb = 0; fb < 4; ++fb) {
            bf16x4 p;
            #pragma unroll
            for (int r = 0; r < 4; ++r) p[r] = f2bf(acc[it][fb][r] + bias[fb]);
            int f = 64 * w + 16 * fb + n16;
            *(bf16x4*)&tr[f * 40 + 16 * it + 4 * quad] = p;
        }
    __syncthreads();
    {
        short* qTs = qT + ((size_t)(i0 >> 9)) * FD * NA;
        const int ilb = i0 & 511;
        #pragma unroll
        for (int n = 0; n < 4; ++n) {
            int S = n * 256 + t;        // 0..1023
            int f = S >> 2;             // 0..255
            int c = S & 3;              // chunk of 8 atoms
            uint4 v = *(const uint4*)&tr[f * 40 + c * 8];
            *(uint4*)&qTs[(size_t)f * NA + ilb + c * 8] = v;
        }
    }
}

// ---------------------------------------------------------------------------
// Kernel 2 v8: V = 0.5 * v @ q (bf16 MFMA), out = V * q. Non-coop, qT in d_ws.
// Same math/index maps as round-7 (PASSED), one scheduling change:
//   bq q-fragment loads are ISSUED AT THE TOP of each j-iteration, before
//   the v-tile trig (~500+ cyc VALU) — the __syncthreads drain then finds
//   them complete, and the MFMA phase consumes registers with no exposed
//   L2/L3 latency (round-7 issued them inside the MFMA phase, distance=0;
//   the barrier is a fence so the compiler could not hoist them itself).
// q never touches LDS (zero cross-wave reuse). svb double-buffered,
// ONE barrier per j-iteration. LDS: 6 KB pos + 16 KB svb = 22 KB.
// bq[4][4] is fully unrolled/statically indexed (no scratch).
// ---------------------------------------------------------------------------
__global__ __launch_bounds__(256, 2) void lr_fast(
    const float* __restrict__ pos, float* __restrict__ gbuf,
    const short* __restrict__ qT)
{
    __shared__ float px[NA], py[NA], pz[NA];
    __shared__ __attribute__((aligned(16))) short svb[2][32 * 128]; // 16 KB

    const int blk = blockIdx.x;
    const int s   = blk & 31;          // XCD-local: 16 blocks of s on XCD s%8
    const int i0  = (blk >> 5) * 32;
    const int t   = threadIdx.x;
    const int w    = t >> 6;
    const int lane = t & 63;
    const int n16  = lane & 15;
    const int quad = lane >> 4;

    for (int m = t; m < NA; m += 256) {
        const float* p = &pos[((size_t)s * NA + m) * 3];
        px[m] = p[0]; py[m] = p[1]; pz[m] = p[2];
    }

    f32x4 acc[2][4];
    #pragma unroll
    for (int a = 0; a < 2; ++a)
        #pragma unroll
        for (int c = 0; c < 4; ++c) acc[a][c] = (f32x4)0.0f;

    const short* qTs = qT + (size_t)s * FD * NA;

    // own-tile q snapshot: qreg[it][fb][r] = q[f][i0+16it+4quad+r], direct.
    float qreg[2][4][4];
    #pragma unroll
    for (int it = 0; it < 2; ++it)
        #pragma unroll
        for (int fb = 0; fb < 4; ++fb) {
            int f = 64 * w + 16 * fb + n16;
            bf16x4 qv = *(const bf16x4*)&qTs[(size_t)f * NA + i0 + 16 * it + 4 * quad];
            #pragma unroll
            for (int r = 0; r < 4; ++r) qreg[it][fb][r] = bf2f(qv[r]);
        }

    const int pi = t & 31;        // pair-tile i
    const int pc = t >> 5;        // pair-tile j-chunk 0..7 (16 j each)
    const int gi = i0 + pi;

    __syncthreads();              // positions ready
    const float xi = px[gi], yi = py[gi], zi = pz[gi];

    int cur = 0;
    for (int j0 = 0; j0 < NA; j0 += 128) {
        // ---- ISSUE q fragments for THIS tile first (T14 issue-early) ----
        bf16x8 bq[4][4];                       // [kh][fb], 64 VGPR, static idx
        #pragma unroll
        for (int kh = 0; kh < 4; ++kh) {
            const int c = kh * 4 + quad;       // logical 8-j chunk 0..15
            #pragma unroll
            for (int fb = 0; fb < 4; ++fb) {
                int f = 64 * w + 16 * fb + n16;
                bq[kh][fb] = *(const bf16x8*)&qTs[(size_t)f * NA + j0 + c * 8];
            }
        }

        // ---- v tile: 32i x 128j (16 pair evals/thread) into svb[cur] ----
        // ~500+ cycles of VALU; covers the bq load latency.
        bf16x8 vA, vB;
        #pragma unroll
        for (int jj = 0; jj < 8; ++jj) {
            int gj = j0 + pc * 16 + jj;
            float dx = xi - px[gj];
            float dy = yi - py[gj];
            float dz = zi - pz[gj];
            float r2 = dx * dx + dy * dy + dz * dz;
            float inv = __builtin_amdgcn_rsqf(r2);
            float dd  = r2 * inv;
            float sn = __sinf(dd * 0.31415926535f);
            float om = (dd < 5.0f) ? sn * sn : 1.0f;
            float vv = (gi != gj) ? 0.5f * om * inv : 0.0f;
            vA[jj] = f2bf(vv);
        }
        #pragma unroll
        for (int jj = 0; jj < 8; ++jj) {
            int gj = j0 + pc * 16 + 8 + jj;
            float dx = xi - px[gj];
            float dy = yi - py[gj];
            float dz = zi - pz[gj];
            float r2 = dx * dx + dy * dy + dz * dz;
            float inv = __builtin_amdgcn_rsqf(r2);
            float dd  = r2 * inv;
            float sn = __sinf(dd * 0.31415926535f);
            float om = (dd < 5.0f) ? sn * sn : 1.0f;
            float vv = (gi != gj) ? 0.5f * om * inv : 0.0f;
            vB[jj] = f2bf(vv);
        }
        *(bf16x8*)&svb[cur][pi * 128 + (((2 * pc + pi) & 15) * 8)]     = vA;
        *(bf16x8*)&svb[cur][pi * 128 + (((2 * pc + 1 + pi) & 15) * 8)] = vB;
        __syncthreads();   // svb[cur] ready; bq loads drained here too

        // ---- MFMA phase: pure register/LDS consumption ----
        #pragma unroll
        for (int kh = 0; kh < 4; ++kh) {
            const int c = kh * 4 + quad;
            bf16x8 a0 = *(const bf16x8*)&svb[cur][n16 * 128 + (((c + n16) & 15) * 8)];
            bf16x8 a1 = *(const bf16x8*)&svb[cur][(16 + n16) * 128 + (((c + 16 + n16) & 15) * 8)];
            __builtin_amdgcn_s_setprio(1);
            #pragma unroll
            for (int fb = 0; fb < 4; ++fb) {
                acc[0][fb] = __builtin_amdgcn_mfma_f32_16x16x32_bf16(
                    a0, bq[kh][fb], acc[0][fb], 0, 0, 0);
                acc[1][fb] = __builtin_amdgcn_mfma_f32_16x16x32_bf16(
                    a1, bq[kh][fb], acc[1][fb], 0, 0, 0);
            }
            __builtin_amdgcn_s_setprio(0);
        }
        cur ^= 1;
    }

    // epilogue: out = V * q  (pure store, q from registers)
    #pragma unroll
    for (int it = 0; it < 2; ++it)
        #pragma unroll
        for (int fb = 0; fb < 4; ++fb)
            #pragma unroll
            for (int r = 0; r < 4; ++r) {
                int i = i0 + 16 * it + 4 * quad + r;
                int f = 64 * w + 16 * fb + n16;
                size_t a = ((size_t)s * NA + i) * FD + f;
                gbuf[a] = acc[it][fb][r] * qreg[it][fb][r];
            }
}

// ---------------------------------------------------------------------------
// FALLBACK kernels (used if ws < 8 MB) — unchanged, validated earlier.
// ---------------------------------------------------------------------------
__global__ __launch_bounds__(512) void charges_mfma(
    const float* __restrict__ feat, const float* __restrict__ W,
    const float* __restrict__ b, float* __restrict__ qfp,
    short* __restrict__ qT)
{
    __shared__ __attribute__((aligned(16))) short sA[64 * 72];
    __shared__ __attribute__((aligned(16))) short sB[256 * 72];
    __shared__ __attribute__((aligned(16))) short tr[256 * 72];
    const int t    = threadIdx.x;
    const int i0   = blockIdx.x * 64;
    const int w    = t >> 6;
    const int lane = t & 63;
    const int n16  = lane & 15;
    const int quad = lane >> 4;

    f32x4 acc[4][2];
    #pragma unroll
    for (int a = 0; a < 4; ++a)
        #pragma unroll
        for (int c = 0; c < 2; ++c) acc[a][c] = (f32x4)0.0f;

    for (int k0 = 0; k0 < FD; k0 += 64) {
        #pragma unroll
        for (int m = 0; m < 2; ++m) {
            int lin = t + 512 * m;
            int i = lin >> 4, kq = lin & 15;
            float4 v = *(const float4*)&feat[(size_t)(i0 + i) * FD + k0 + 4 * kq];
            bf16x4 p; p[0] = f2bf(v.x); p[1] = f2bf(v.y);
                      p[2] = f2bf(v.z); p[3] = f2bf(v.w);
            *(bf16x4*)&sA[i * 72 + 4 * kq] = p;
        }
        #pragma unroll
        for (int m = 0; m < 8; ++m) {
            int lin = t + 512 * m;
            int f = lin >> 4, kq = lin & 15;
            float4 v = *(const float4*)&W[(size_t)f * FD + k0 + 4 * kq];
            bf16x4 p; p[0] = f2bf(v.x); p[1] = f2bf(v.y);
                      p[2] = f2bf(v.z); p[3] = f2bf(v.w);
            *(bf16x4*)&sB[f * 72 + 4 * kq] = p;
        }
        __syncthreads();

        #pragma unroll
        for (int ks = 0; ks < 64; ks += 32) {
            bf16x8 af[4], bfr[2];
            #pragma unroll
            for (int it = 0; it < 4; ++it)
                af[it] = *(const bf16x8*)&sA[(16 * it + n16) * 72 + ks + quad * 8];
            #pragma unroll
            for (int fb = 0; fb < 2; ++fb)
                bfr[fb] = *(const bf16x8*)&sB[(32 * w + 16 * fb + n16) * 72 + ks + quad * 8];
            #pragma unroll
            for (int it = 0; it < 4; ++it)
                #pragma unroll
                for (int fb = 0; fb < 2; ++fb)
                    acc[it][fb] = __builtin_amdgcn_mfma_f32_16x16x32_bf16(
                        af[it], bfr[fb], acc[it][fb], 0, 0, 0);
        }
        __syncthreads();
    }

    float bias[2];
    #pragma unroll
    for (int fb = 0; fb < 2; ++fb) bias[fb] = b[32 * w + 16 * fb + n16];

    if (qfp) {
        #pragma unroll
        for (int it = 0; it < 4; ++it)
            #pragma unroll
            for (int fb = 0; fb < 2; ++fb)
                #pragma unroll
                for (int r = 0; r < 4; ++r) {
                    int i = i0 + 16 * it + 4 * quad + r;
                    int f = 32 * w + 16 * fb + n16;
                    qfp[(size_t)i * FD + f] = acc[it][fb][r] + bias[fb];
                }
    }

    #pragma unroll
    for (int it = 0; it < 4; ++it)
        #pragma unroll
        for (int fb = 0; fb < 2; ++fb) {
            bf16x4 p;
            #pragma unroll
            for (int r = 0; r < 4; ++r) p[r] = f2bf(acc[it][fb][r] + bias[fb]);
            int f = 32 * w + 16 * fb + n16;
            *(bf16x4*)&tr[f * 72 + 16 * it + 4 * quad] = p;
        }
    __syncthreads();
    {
        short* qTs = qT + ((size_t)(i0 >> 9)) * FD * NA;
        const int ilb = i0 & 511;
        #pragma unroll
        for (int n = 0; n < 4; ++n) {
            int S = n * 512 + t;
            int f = S >> 3;
            int c = S & 7;
            uint4 v = *(const uint4*)&tr[f * 72 + c * 8];
            *(uint4*)&qTs[(size_t)f * NA + ilb + c * 8] = v;
        }
    }
}

__global__ __launch_bounds__(256) void lr_coop(
    const float* __restrict__ pos, float* __restrict__ gbuf)
{
    __shared__ float px[NA], py[NA], pz[NA];
    __shared__ __attribute__((aligned(16))) short svb[64 * 40];
    __shared__ __attribute__((aligned(16))) short sqb[FD * 40];

    const int blk = blockIdx.x;
    const int s   = blk & 31;
    const int i0  = (blk >> 5) * 64;
    const int t   = threadIdx.x;
    const int w    = t >> 6;
    const int lane = t & 63;
    const int n16  = lane & 15;
    const int quad = lane >> 4;

    for (int m = t; m < NA; m += 256) {
        const float* p = &pos[((size_t)s * NA + m) * 3];
        px[m] = p[0]; py[m] = p[1]; pz[m] = p[2];
    }

    f32x4 acc[4][4];
    #pragma unroll
    for (int a = 0; a < 4; ++a)
        #pragma unroll
        for (int c = 0; c < 4; ++c) acc[a][c] = (f32x4)0.0f;

    __syncthreads();

    const int fq  = t >> 2;
    const int jb  = t & 3;
    const int iv  = t & 63;
    const int jbv = t >> 6;
    const int gi  = i0 + iv;

    float4 rq[8];
    #pragma unroll
    for (int m = 0; m < 8; ++m)
        rq[m] = *(const float4*)&gbuf[((size_t)s * NA + 8 * jb + m) * FD + 4 * fq];

    for (int j0 = 0; j0 < NA; j0 += 32) {
        bf16x8 vrow;
        #pragma unroll
        for (int jj = 0; jj < 8; ++jj) {
            int gj = j0 + 8 * jbv + jj;
            float dx = px[gi] - px[gj];
            float dy = py[gi] - py[gj];
            float dz = pz[gi] - pz[gj];
            float dd = sqrtf(dx * dx + dy * dy + dz * dz);
            float om = (dd < 5.0f) ? 0.5f * (1.0f - __cosf(dd * 0.62831853071795f))
                                   : 1.0f;
            float vv = (gi != gj) ? (0.5f * om * __builtin_amdgcn_rcpf(dd)) : 0.0f;
            vrow[jj] = f2bf(vv);
        }
        bf16x8 rows[4];
        #pragma unroll
        for (int m = 0; m < 8; ++m) {
            rows[0][m] = f2bf(rq[m].x);
            rows[1][m] = f2bf(rq[m].y);
            rows[2][m] = f2bf(rq[m].z);
            rows[3][m] = f2bf(rq[m].w);
        }
        #pragma unroll
        for (int d = 0; d < 4; ++d) {
            int f = 4 * fq + d;
            int phys = (jb + (f >> 3)) & 3;
            *(bf16x8*)&sqb[f * 40 + phys * 8] = rows[d];
        }
        {
            int phys = (jbv + (iv >> 3)) & 3;
            *(bf16x8*)&svb[iv * 40 + phys * 8] = vrow;
        }
        {
            int jn = (j0 + 32) & (NA - 1);
            #pragma unroll
            for (int m = 0; m < 8; ++m)
                rq[m] = *(const float4*)&gbuf[((size_t)s * NA + jn + 8 * jb + m) * FD + 4 * fq];
        }
        __syncthreads();

        bf16x8 af[4], bfr[4];
        #pragma unroll
        for (int it = 0; it < 4; ++it) {
            int i = 16 * it + n16;
            int phys = (quad + (i >> 3)) & 3;
            af[it] = *(const bf16x8*)&svb[i * 40 + phys * 8];
        }
        #pragma unroll
        for (int fb = 0; fb < 4; ++fb) {
            int f = 16 * (4 * w + fb) + n16;
            int phys = (quad + (f >> 3)) & 3;
            bfr[fb] = *(const bf16x8*)&sqb[f * 40 + phys * 8];
        }
        #pragma unroll
        for (int it = 0; it < 4; ++it)
            #pragma unroll
            for (int fb = 0; fb < 4; ++fb)
                acc[it][fb] = __builtin_amdgcn_mfma_f32_16x16x32_bf16(
                    af[it], bfr[fb], acc[it][fb], 0, 0, 0);
        __syncthreads();
    }

    cooperative_groups::this_grid().sync();

    #pragma unroll
    for (int it = 0; it < 4; ++it)
        #pragma unroll
        for (int fb = 0; fb < 4; ++fb)
            #pragma unroll
            for (int r = 0; r < 4; ++r) {
                int i = i0 + 16 * it + 4 * quad + r;
                int f = 16 * (4 * w + fb) + n16;
                size_t a = ((size_t)s * NA + i) * FD + f;
                gbuf[a] = acc[it][fb][r] * gbuf[a];
            }
}

extern "C" void kernel_launch(void* const* d_in, const int* in_sizes, int n_in,
                              void* d_out, int out_size, void* d_ws, size_t ws_size,
                              hipStream_t stream) {
    const float* positions = (const float*)d_in[0];  // [32,512,3]
    const float* features  = (const float*)d_in[1];  // [16384,256]
    const float* W         = (const float*)d_in[2];  // [256,256]
    const float* b         = (const float*)d_in[3];  // [256]
    float* gbuf = (float*)d_out;

    const size_t qT_bytes = (size_t)SY * NA * FD * sizeof(short);  // 8 MB
    const bool fast = (ws_size >= qT_bytes);
    short* qT = fast ? (short*)d_ws : nullptr;

    if (fast) {
        charges_v2<<<dim3(512), 256, 0, stream>>>(features, W, b, qT);
        lr_fast<<<dim3(512), 256, 0, stream>>>(positions, gbuf, qT);
    } else {
        // fallback: q fp32 in d_out, cooperative in-place update
        charges_mfma<<<dim3(256), 512, 0, stream>>>(features, W, b, gbuf,
                                                    (short*)d_out /*unused-safe*/);
        void* args[] = {(void*)&positions, (void*)&gbuf};
        hipLaunchCooperativeKernel((void*)lr_coop, dim3(256), dim3(256),
                                   args, 0, stream);
    }
}

// Round 9
// 98.510 us; speedup vs baseline: 1.3760x; 1.0384x over previous
//
#include <hip/hip_runtime.h>
#include <hip/hip_cooperative_groups.h>

// S=32 systems, N=512 atoms/system, F=256 features
#define SY 32
#define NA 512
#define FD 256

typedef __attribute__((ext_vector_type(8))) short bf16x8;   // 8 bf16 = 4 VGPRs
typedef __attribute__((ext_vector_type(4))) short bf16x4;   // 4 bf16 = 8 B
typedef __attribute__((ext_vector_type(4))) float f32x4;    // MFMA C/D frag

static __device__ __forceinline__ short f2bf(float x) {
    union { float f; unsigned u; } v; v.f = x;
    unsigned r = v.u + 0x7fffu + ((v.u >> 16) & 1u);   // RNE
    return (short)(r >> 16);
}
static __device__ __forceinline__ float bf2f(short x) {
    union { float f; unsigned u; } v;
    v.u = ((unsigned)(unsigned short)x) << 16;
    return v.f;
}

// async 16B global->LDS (linear dest = wave-uniform base + lane*16)
static __device__ __forceinline__ void gld16(const void* g, void* l) {
    __builtin_amdgcn_global_load_lds(
        (const __attribute__((address_space(1))) void*)g,
        (__attribute__((address_space(3))) void*)l,
        16, 0, 0);
}

// ---------------------------------------------------------------------------
// Kernel 1 (EXACT round-3, validated 96.5 µs config):
// charges = features @ W^T + b via bf16 MFMA (fp32 accum).
// 512 blocks x 256 threads, 32-row tiles, LDS 41.5 KB -> 2 blocks/CU.
// ---------------------------------------------------------------------------
__global__ __launch_bounds__(256, 2) void charges_v2(
    const float* __restrict__ feat, const float* __restrict__ W,
    const float* __restrict__ b, short* __restrict__ qT)
{
    __shared__ __attribute__((aligned(16))) short sA[32 * 72];   //  4.6 KB
    __shared__ __attribute__((aligned(16))) short sB[256 * 72];  // 36.9 KB
    short* tr = sB;                          // epilogue reuse: 256*40 shorts
    const int t    = threadIdx.x;
    const int i0   = blockIdx.x * 32;        // 512 blocks x 32 rows
    const int w    = t >> 6;                 // wave 0..3
    const int lane = t & 63;
    const int n16  = lane & 15;
    const int quad = lane >> 4;

    f32x4 acc[2][4];
    #pragma unroll
    for (int a = 0; a < 2; ++a)
        #pragma unroll
        for (int c = 0; c < 4; ++c) acc[a][c] = (f32x4)0.0f;

    for (int k0 = 0; k0 < FD; k0 += 64) {
        // stage feat tile 32i x 64k (2 float4/thread)
        #pragma unroll
        for (int m = 0; m < 2; ++m) {
            int lin = t + 256 * m;
            int i = lin >> 4, kq = lin & 15;
            float4 v = *(const float4*)&feat[(size_t)(i0 + i) * FD + k0 + 4 * kq];
            bf16x4 p; p[0] = f2bf(v.x); p[1] = f2bf(v.y);
                      p[2] = f2bf(v.z); p[3] = f2bf(v.w);
            *(bf16x4*)&sA[i * 72 + 4 * kq] = p;
        }
        // stage W tile 256f x 64k (16 float4/thread)
        #pragma unroll
        for (int m = 0; m < 16; ++m) {
            int lin = t + 256 * m;
            int f = lin >> 4, kq = lin & 15;
            float4 v = *(const float4*)&W[(size_t)f * FD + k0 + 4 * kq];
            bf16x4 p; p[0] = f2bf(v.x); p[1] = f2bf(v.y);
                      p[2] = f2bf(v.z); p[3] = f2bf(v.w);
            *(bf16x4*)&sB[f * 72 + 4 * kq] = p;
        }
        __syncthreads();

        #pragma unroll
        for (int ks = 0; ks < 64; ks += 32) {
            bf16x8 af[2], bfr[4];
            #pragma unroll
            for (int it = 0; it < 2; ++it)
                af[it] = *(const bf16x8*)&sA[(16 * it + n16) * 72 + ks + quad * 8];
            #pragma unroll
            for (int fb = 0; fb < 4; ++fb)
                bfr[fb] = *(const bf16x8*)&sB[(64 * w + 16 * fb + n16) * 72 + ks + quad * 8];
            __builtin_amdgcn_s_setprio(1);
            #pragma unroll
            for (int it = 0; it < 2; ++it)
                #pragma unroll
                for (int fb = 0; fb < 4; ++fb)
                    acc[it][fb] = __builtin_amdgcn_mfma_f32_16x16x32_bf16(
                        af[it], bfr[fb], acc[it][fb], 0, 0, 0);
            __builtin_amdgcn_s_setprio(0);
        }
        __syncthreads();
    }

    float bias[4];
    #pragma unroll
    for (int fb = 0; fb < 4; ++fb) bias[fb] = b[64 * w + 16 * fb + n16];

    // transpose to [f][i] bf16 (pitch 40) in reused sB, then 16B stores
    #pragma unroll
    for (int it = 0; it < 2; ++it)
        #pragma unroll
        for (int fb = 0; fb < 4; ++fb) {
            bf16x4 p;
            #pragma unroll
            for (int r = 0; r < 4; ++r) p[r] = f2bf(acc[it][fb][r] + bias[fb]);
            int f = 64 * w + 16 * fb + n16;
            *(bf16x4*)&tr[f * 40 + 16 * it + 4 * quad] = p;
        }
    __syncthreads();
    {
        short* qTs = qT + ((size_t)(i0 >> 9)) * FD * NA;
        const int ilb = i0 & 511;
        #pragma unroll
        for (int n = 0; n < 4; ++n) {
            int S = n * 256 + t;        // 0..1023
            int f = S >> 2;             // 0..255
            int c = S & 3;              // chunk of 8 atoms
            uint4 v = *(const uint4*)&tr[f * 40 + c * 8];
            *(uint4*)&qTs[(size_t)f * NA + ilb + c * 8] = v;
        }
    }
}

// ---------------------------------------------------------------------------
// Kernel 2 (round-3 gld16-staged lr, validated 96.5 µs config), with the
// ONE micro-edit validated in rounds 7 & 8 (both PASSED): the own-tile q
// snapshot loads DIRECTLY from global qT before the loop, replacing the
// in-loop uniform-branch LDS read. Everything else identical to round 3.
// ---------------------------------------------------------------------------
__global__ __launch_bounds__(256, 2) void lr_fast(
    const float* __restrict__ pos, float* __restrict__ gbuf,
    const short* __restrict__ qT)
{
    __shared__ float px[NA], py[NA], pz[NA];
    __shared__ __attribute__((aligned(16))) short sqb[FD * 128];  // 64 KB [f][128j swz]
    __shared__ __attribute__((aligned(16))) short svb[32 * 128];  //  8 KB [i][128j swz]

    const int blk = blockIdx.x;
    const int s   = blk & 31;
    const int i0  = (blk >> 5) * 32;
    const int t   = threadIdx.x;
    const int w    = t >> 6;
    const int lane = t & 63;
    const int n16  = lane & 15;
    const int quad = lane >> 4;

    for (int m = t; m < NA; m += 256) {
        const float* p = &pos[((size_t)s * NA + m) * 3];
        px[m] = p[0]; py[m] = p[1]; pz[m] = p[2];
    }

    f32x4 acc[2][4];
    #pragma unroll
    for (int a = 0; a < 2; ++a)
        #pragma unroll
        for (int c = 0; c < 4; ++c) acc[a][c] = (f32x4)0.0f;

    const short* qTs = qT + (size_t)s * FD * NA;

    // own-tile q snapshot: direct global loads (validated R7/R8)
    float qreg[2][4][4];
    #pragma unroll
    for (int it = 0; it < 2; ++it)
        #pragma unroll
        for (int fb = 0; fb < 4; ++fb) {
            int f = 64 * w + 16 * fb + n16;
            bf16x4 qv = *(const bf16x4*)&qTs[(size_t)f * NA + i0 + 16 * it + 4 * quad];
            #pragma unroll
            for (int r = 0; r < 4; ++r) qreg[it][fb][r] = bf2f(qv[r]);
        }

    const int pi = t & 31;        // pair-tile i
    const int pc = t >> 5;        // pair-tile j-chunk 0..7 (16 j each)
    const int gi = i0 + pi;
    const int wbase = t & ~63;    // w*64, wave-uniform

    __syncthreads();
    const float xi = px[gi], yi = py[gi], zi = pz[gi];

    for (int j0 = 0; j0 < NA; j0 += 128) {
        // ---- stage q tile: 256f x 128j bf16 via global_load_lds -----------
        // linear LDS slot Sl = n*256 + t holds row f=Sl>>4, phys chunk cs=Sl&15,
        // sourced from logical chunk c=(cs-f)&15 -> read swizzle is (c+f)&15.
        #pragma unroll
        for (int n = 0; n < 16; ++n) {
            int Sl = n * 256 + t;
            int f  = Sl >> 4;
            int cs = Sl & 15;
            int c  = (cs - f) & 15;
            gld16(&qTs[(size_t)f * NA + j0 + c * 8],
                  &sqb[(n * 256 + wbase) * 8]);     // uniform base + lane*16
        }
        // ---- v tile: 32i x 128j (16 pair evals/thread, hides load lat) ----
        bf16x8 vA, vB;
        #pragma unroll
        for (int jj = 0; jj < 8; ++jj) {
            int gj = j0 + pc * 16 + jj;
            float dx = xi - px[gj];
            float dy = yi - py[gj];
            float dz = zi - pz[gj];
            float r2 = dx * dx + dy * dy + dz * dz;
            float inv = __builtin_amdgcn_rsqf(r2);
            float dd  = r2 * inv;
            float sn = __sinf(dd * 0.31415926535f);
            float om = (dd < 5.0f) ? sn * sn : 1.0f;
            float vv = (gi != gj) ? 0.5f * om * inv : 0.0f;
            vA[jj] = f2bf(vv);
        }
        #pragma unroll
        for (int jj = 0; jj < 8; ++jj) {
            int gj = j0 + pc * 16 + 8 + jj;
            float dx = xi - px[gj];
            float dy = yi - py[gj];
            float dz = zi - pz[gj];
            float r2 = dx * dx + dy * dy + dz * dz;
            float inv = __builtin_amdgcn_rsqf(r2);
            float dd  = r2 * inv;
            float sn = __sinf(dd * 0.31415926535f);
            float om = (dd < 5.0f) ? sn * sn : 1.0f;
            float vv = (gi != gj) ? 0.5f * om * inv : 0.0f;
            vB[jj] = f2bf(vv);
        }
        *(bf16x8*)&svb[pi * 128 + (((2 * pc + pi) & 15) * 8)]     = vA;
        *(bf16x8*)&svb[pi * 128 + (((2 * pc + 1 + pi) & 15) * 8)] = vB;
        __syncthreads();

        // ---- fragments + MFMA: 4 kh x (2 it x 4 fb) = 32 mfma / wave ----
        #pragma unroll
        for (int kh = 0; kh < 4; ++kh) {
            const int c = kh * 4 + quad;          // logical 8-j chunk 0..15
            bf16x8 a0 = *(const bf16x8*)&svb[n16 * 128 + (((c + n16) & 15) * 8)];
            bf16x8 a1 = *(const bf16x8*)&svb[(16 + n16) * 128 + (((c + 16 + n16) & 15) * 8)];
            bf16x8 bq[4];
            #pragma unroll
            for (int fb = 0; fb < 4; ++fb) {
                int f = 64 * w + 16 * fb + n16;
                bq[fb] = *(const bf16x8*)&sqb[f * 128 + (((c + f) & 15) * 8)];
            }
            __builtin_amdgcn_s_setprio(1);
            #pragma unroll
            for (int fb = 0; fb < 4; ++fb) {
                acc[0][fb] = __builtin_amdgcn_mfma_f32_16x16x32_bf16(
                    a0, bq[fb], acc[0][fb], 0, 0, 0);
                acc[1][fb] = __builtin_amdgcn_mfma_f32_16x16x32_bf16(
                    a1, bq[fb], acc[1][fb], 0, 0, 0);
            }
            __builtin_amdgcn_s_setprio(0);
        }
        __syncthreads();
    }

    // epilogue: out = V * q  (pure store, q from registers)
    #pragma unroll
    for (int it = 0; it < 2; ++it)
        #pragma unroll
        for (int fb = 0; fb < 4; ++fb)
            #pragma unroll
            for (int r = 0; r < 4; ++r) {
                int i = i0 + 16 * it + 4 * quad + r;
                int f = 64 * w + 16 * fb + n16;
                size_t a = ((size_t)s * NA + i) * FD + f;
                gbuf[a] = acc[it][fb][r] * qreg[it][fb][r];
            }
}

// ---------------------------------------------------------------------------
// FALLBACK kernels (used if ws < 8 MB) — unchanged, validated earlier.
// ---------------------------------------------------------------------------
__global__ __launch_bounds__(512) void charges_mfma(
    const float* __restrict__ feat, const float* __restrict__ W,
    const float* __restrict__ b, float* __restrict__ qfp,
    short* __restrict__ qT)
{
    __shared__ __attribute__((aligned(16))) short sA[64 * 72];
    __shared__ __attribute__((aligned(16))) short sB[256 * 72];
    __shared__ __attribute__((aligned(16))) short tr[256 * 72];
    const int t    = threadIdx.x;
    const int i0   = blockIdx.x * 64;
    const int w    = t >> 6;
    const int lane = t & 63;
    const int n16  = lane & 15;
    const int quad = lane >> 4;

    f32x4 acc[4][2];
    #pragma unroll
    for (int a = 0; a < 4; ++a)
        #pragma unroll
        for (int c = 0; c < 2; ++c) acc[a][c] = (f32x4)0.0f;

    for (int k0 = 0; k0 < FD; k0 += 64) {
        #pragma unroll
        for (int m = 0; m < 2; ++m) {
            int lin = t + 512 * m;
            int i = lin >> 4, kq = lin & 15;
            float4 v = *(const float4*)&feat[(size_t)(i0 + i) * FD + k0 + 4 * kq];
            bf16x4 p; p[0] = f2bf(v.x); p[1] = f2bf(v.y);
                      p[2] = f2bf(v.z); p[3] = f2bf(v.w);
            *(bf16x4*)&sA[i * 72 + 4 * kq] = p;
        }
        #pragma unroll
        for (int m = 0; m < 8; ++m) {
            int lin = t + 512 * m;
            int f = lin >> 4, kq = lin & 15;
            float4 v = *(const float4*)&W[(size_t)f * FD + k0 + 4 * kq];
            bf16x4 p; p[0] = f2bf(v.x); p[1] = f2bf(v.y);
                      p[2] = f2bf(v.z); p[3] = f2bf(v.w);
            *(bf16x4*)&sB[f * 72 + 4 * kq] = p;
        }
        __syncthreads();

        #pragma unroll
        for (int ks = 0; ks < 64; ks += 32) {
            bf16x8 af[4], bfr[2];
            #pragma unroll
            for (int it = 0; it < 4; ++it)
                af[it] = *(const bf16x8*)&sA[(16 * it + n16) * 72 + ks + quad * 8];
            #pragma unroll
            for (int fb = 0; fb < 2; ++fb)
                bfr[fb] = *(const bf16x8*)&sB[(32 * w + 16 * fb + n16) * 72 + ks + quad * 8];
            #pragma unroll
            for (int it = 0; it < 4; ++it)
                #pragma unroll
                for (int fb = 0; fb < 2; ++fb)
                    acc[it][fb] = __builtin_amdgcn_mfma_f32_16x16x32_bf16(
                        af[it], bfr[fb], acc[it][fb], 0, 0, 0);
        }
        __syncthreads();
    }

    float bias[2];
    #pragma unroll
    for (int fb = 0; fb < 2; ++fb) bias[fb] = b[32 * w + 16 * fb + n16];

    if (qfp) {
        #pragma unroll
        for (int it = 0; it < 4; ++it)
            #pragma unroll
            for (int fb = 0; fb < 2; ++fb)
                #pragma unroll
                for (int r = 0; r < 4; ++r) {
                    int i = i0 + 16 * it + 4 * quad + r;
                    int f = 32 * w + 16 * fb + n16;
                    qfp[(size_t)i * FD + f] = acc[it][fb][r] + bias[fb];
                }
    }

    #pragma unroll
    for (int it = 0; it < 4; ++it)
        #pragma unroll
        for (int fb = 0; fb < 2; ++fb) {
            bf16x4 p;
            #pragma unroll
            for (int r = 0; r < 4; ++r) p[r] = f2bf(acc[it][fb][r] + bias[fb]);
            int f = 32 * w + 16 * fb + n16;
            *(bf16x4*)&tr[f * 72 + 16 * it + 4 * quad] = p;
        }
    __syncthreads();
    {
        short* qTs = qT + ((size_t)(i0 >> 9)) * FD * NA;
        const int ilb = i0 & 511;
        #pragma unroll
        for (int n = 0; n < 4; ++n) {
            int S = n * 512 + t;
            int f = S >> 3;
            int c = S & 7;
            uint4 v = *(const uint4*)&tr[f * 72 + c * 8];
            *(uint4*)&qTs[(size_t)f * NA + ilb + c * 8] = v;
        }
    }
}

__global__ __launch_bounds__(256) void lr_coop(
    const float* __restrict__ pos, float* __restrict__ gbuf)
{
    __shared__ float px[NA], py[NA], pz[NA];
    __shared__ __attribute__((aligned(16))) short svb[64 * 40];
    __shared__ __attribute__((aligned(16))) short sqb[FD * 40];

    const int blk = blockIdx.x;
    const int s   = blk & 31;
    const int i0  = (blk >> 5) * 64;
    const int t   = threadIdx.x;
    const int w    = t >> 6;
    const int lane = t & 63;
    const int n16  = lane & 15;
    const int quad = lane >> 4;

    for (int m = t; m < NA; m += 256) {
        const float* p = &pos[((size_t)s * NA + m) * 3];
        px[m] = p[0]; py[m] = p[1]; pz[m] = p[2];
    }

    f32x4 acc[4][4];
    #pragma unroll
    for (int a = 0; a < 4; ++a)
        #pragma unroll
        for (int c = 0; c < 4; ++c) acc[a][c] = (f32x4)0.0f;

    __syncthreads();

    const int fq  = t >> 2;
    const int jb  = t & 3;
    const int iv  = t & 63;
    const int jbv = t >> 6;
    const int gi  = i0 + iv;

    float4 rq[8];
    #pragma unroll
    for (int m = 0; m < 8; ++m)
        rq[m] = *(const float4*)&gbuf[((size_t)s * NA + 8 * jb + m) * FD + 4 * fq];

    for (int j0 = 0; j0 < NA; j0 += 32) {
        bf16x8 vrow;
        #pragma unroll
        for (int jj = 0; jj < 8; ++jj) {
            int gj = j0 + 8 * jbv + jj;
            float dx = px[gi] - px[gj];
            float dy = py[gi] - py[gj];
            float dz = pz[gi] - pz[gj];
            float dd = sqrtf(dx * dx + dy * dy + dz * dz);
            float om = (dd < 5.0f) ? 0.5f * (1.0f - __cosf(dd * 0.62831853071795f))
                                   : 1.0f;
            float vv = (gi != gj) ? (0.5f * om * __builtin_amdgcn_rcpf(dd)) : 0.0f;
            vrow[jj] = f2bf(vv);
        }
        bf16x8 rows[4];
        #pragma unroll
        for (int m = 0; m < 8; ++m) {
            rows[0][m] = f2bf(rq[m].x);
            rows[1][m] = f2bf(rq[m].y);
            rows[2][m] = f2bf(rq[m].z);
            rows[3][m] = f2bf(rq[m].w);
        }
        #pragma unroll
        for (int d = 0; d < 4; ++d) {
            int f = 4 * fq + d;
            int phys = (jb + (f >> 3)) & 3;
            *(bf16x8*)&sqb[f * 40 + phys * 8] = rows[d];
        }
        {
            int phys = (jbv + (iv >> 3)) & 3;
            *(bf16x8*)&svb[iv * 40 + phys * 8] = vrow;
        }
        {
            int jn = (j0 + 32) & (NA - 1);
            #pragma unroll
            for (int m = 0; m < 8; ++m)
                rq[m] = *(const float4*)&gbuf[((size_t)s * NA + jn + 8 * jb + m) * FD + 4 * fq];
        }
        __syncthreads();

        bf16x8 af[4], bfr[4];
        #pragma unroll
        for (int it = 0; it < 4; ++it) {
            int i = 16 * it + n16;
            int phys = (quad + (i >> 3)) & 3;
            af[it] = *(const bf16x8*)&svb[i * 40 + phys * 8];
        }
        #pragma unroll
        for (int fb = 0; fb < 4; ++fb) {
            int f = 16 * (4 * w + fb) + n16;
            int phys = (quad + (f >> 3)) & 3;
            bfr[fb] = *(const bf16x8*)&sqb[f * 40 + phys * 8];
        }
        #pragma unroll
        for (int it = 0; it < 4; ++it)
            #pragma unroll
            for (int fb = 0; fb < 4; ++fb)
                acc[it][fb] = __builtin_amdgcn_mfma_f32_16x16x32_bf16(
                    af[it], bfr[fb], acc[it][fb], 0, 0, 0);
        __syncthreads();
    }

    cooperative_groups::this_grid().sync();

    #pragma unroll
    for (int it = 0; it < 4; ++it)
        #pragma unroll
        for (int fb = 0; fb < 4; ++fb)
            #pragma unroll
            for (int r = 0; r < 4; ++r) {
                int i = i0 + 16 * it + 4 * quad + r;
                int f = 16 * (4 * w + fb) + n16;
                size_t a = ((size_t)s * NA + i) * FD + f;
                gbuf[a] = acc[it][fb][r] * gbuf[a];
            }
}

extern "C" void kernel_launch(void* const* d_in, const int* in_sizes, int n_in,
                              void* d_out, int out_size, void* d_ws, size_t ws_size,
                              hipStream_t stream) {
    const float* positions = (const float*)d_in[0];  // [32,512,3]
    const float* features  = (const float*)d_in[1];  // [16384,256]
    const float* W         = (const float*)d_in[2];  // [256,256]
    const float* b         = (const float*)d_in[3];  // [256]
    float* gbuf = (float*)d_out;

    const size_t qT_bytes = (size_t)SY * NA * FD * sizeof(short);  // 8 MB
    const bool fast = (ws_size >= qT_bytes);
    short* qT = fast ? (short*)d_ws : nullptr;

    if (fast) {
        charges_v2<<<dim3(512), 256, 0, stream>>>(features, W, b, qT);
        lr_fast<<<dim3(512), 256, 0, stream>>>(positions, gbuf, qT);
    } else {
        // fallback: q fp32 in d_out, cooperative in-place update
        charges_mfma<<<dim3(256), 512, 0, stream>>>(features, W, b, gbuf,
                                                    (short*)d_out /*unused-safe*/);
        void* args[] = {(void*)&positions, (void*)&gbuf};
        hipLaunchCooperativeKernel((void*)lr_coop, dim3(256), dim3(256),
                                   args, 0, stream);
    }
}